// Round 1
// baseline (184.520 us; speedup 1.0000x reference)
//
#include <hip/hip_runtime.h>
#include <hip/hip_bf16.h>

// out[b][n] = dot(x[b][n][:], W[n][:]) + bias[n]
// B=128, N=1024, S=2048, all fp32. Memory-bound: ~1.08 GB read.
// One wave (64 lanes) per output element; float4 coalesced loads;
// __shfl_xor wave reduction (width 64).

#define B_DIM 128
#define N_DIM 1024
#define S_DIM 2048

__global__ __launch_bounds__(256) void
neuron_dot_kernel(const float* __restrict__ x,
                  const float* __restrict__ W,
                  const float* __restrict__ bias,
                  float* __restrict__ out) {
    const int wave = threadIdx.x >> 6;      // 0..3
    const int lane = threadIdx.x & 63;
    const long long idx = (long long)blockIdx.x * 4 + wave;   // output index in [0, B*N)
    const int ni = (int)(idx & (N_DIM - 1));                   // idx % N

    const float* __restrict__ xr = x + idx * (long long)S_DIM;
    const float* __restrict__ wr = W + (long long)ni * S_DIM;

    float acc = 0.0f;
    #pragma unroll
    for (int it = 0; it < S_DIM / 256; ++it) {                 // 8 iterations
        const int off = it * 256 + lane * 4;
        const float4 xv = *reinterpret_cast<const float4*>(xr + off);
        const float4 wv = *reinterpret_cast<const float4*>(wr + off);
        acc += xv.x * wv.x;
        acc += xv.y * wv.y;
        acc += xv.z * wv.z;
        acc += xv.w * wv.w;
    }

    // wave-wide tree reduction (64 lanes)
    #pragma unroll
    for (int s = 32; s >= 1; s >>= 1)
        acc += __shfl_xor(acc, s, 64);

    if (lane == 0)
        out[idx] = acc + bias[ni];
}

extern "C" void kernel_launch(void* const* d_in, const int* in_sizes, int n_in,
                              void* d_out, int out_size, void* d_ws, size_t ws_size,
                              hipStream_t stream) {
    const float* x    = (const float*)d_in[0];   // [B, N, S]
    const float* W    = (const float*)d_in[1];   // [N, S]
    const float* bias = (const float*)d_in[2];   // [N]
    float* out        = (float*)d_out;           // [B, N]

    const int total_outputs = B_DIM * N_DIM;     // 131072
    const int blocks = total_outputs / 4;        // 4 waves per 256-thread block

    neuron_dot_kernel<<<blocks, 256, 0, stream>>>(x, W, bias, out);
}

// Round 2
// 171.720 us; speedup vs baseline: 1.0745x; 1.0745x over previous
//
#include <hip/hip_runtime.h>
#include <hip/hip_bf16.h>

// out[b][n] = dot(x[b][n][:], W[n][:]) + bias[n]
// B=128, N=1024, S=2048, fp32. Memory-bound (~1.08 GB x-stream).
//
// Structure: 2048 blocks x 256 threads = 8192 waves. Wave wid owns neuron
// n = wid & 1023 and batches b = (wid>>10) + 8k, k=0..15.
//   - W row (8 KB) loaded ONCE into 32 VGPRs, reused for 16 x-rows.
//   - x rows loaded nontemporal (zero reuse -> don't thrash L2),
//     double-buffered with static buffer index (k&1, unroll 2).
//   - 64-lane __shfl_xor tree reduction per output.

#define B_DIM 128
#define N_DIM 1024
#define S_DIM 2048
#define OUTS_PER_WAVE 16   // = B_DIM / 8 wave-groups

typedef float f32x4 __attribute__((ext_vector_type(4)));

__device__ __forceinline__ f32x4 nt_load4(const float* p) {
    return __builtin_nontemporal_load(reinterpret_cast<const f32x4*>(p));
}

__global__ __launch_bounds__(256, 4) void
neuron_dot_kernel(const float* __restrict__ x,
                  const float* __restrict__ W,
                  const float* __restrict__ bias,
                  float* __restrict__ out) {
    const int wave = threadIdx.x >> 6;           // 0..3
    const int lane = threadIdx.x & 63;
    const int wid  = blockIdx.x * 4 + wave;      // 0..8191
    const int n    = wid & (N_DIM - 1);          // neuron owned by this wave
    const int b0   = wid >> 10;                  // 0..7

    const float* __restrict__ wr = W + (long long)n * S_DIM;
    const float bv = bias[n];

    // --- load W row into registers (8 x float4 per lane = full 8 KB row) ---
    f32x4 w[8];
    #pragma unroll
    for (int it = 0; it < 8; ++it)
        w[it] = *reinterpret_cast<const f32x4*>(wr + it * 256 + lane * 4);

    // --- x row base for k=0; advance by 8 batches per iteration ---
    const long long xstride = 8LL * N_DIM * S_DIM;          // floats per k-step
    const float* xr = x + ((long long)b0 * N_DIM + n) * S_DIM;

    f32x4 buf[2][8];
    #pragma unroll
    for (int it = 0; it < 8; ++it)
        buf[0][it] = nt_load4(xr + it * 256 + lane * 4);

    #pragma unroll 2
    for (int k = 0; k < OUTS_PER_WAVE; ++k) {
        const f32x4* cur = buf[k & 1];
        f32x4*       nxt = buf[(k + 1) & 1];

        // prefetch next x row while we compute on the current one
        if (k + 1 < OUTS_PER_WAVE) {
            const float* xn = xr + xstride;
            #pragma unroll
            for (int it = 0; it < 8; ++it)
                nxt[it] = nt_load4(xn + it * 256 + lane * 4);
        }

        float acc = 0.0f;
        #pragma unroll
        for (int it = 0; it < 8; ++it) {
            acc += cur[it][0] * w[it][0];
            acc += cur[it][1] * w[it][1];
            acc += cur[it][2] * w[it][2];
            acc += cur[it][3] * w[it][3];
        }

        // 64-lane tree reduction
        #pragma unroll
        for (int s = 32; s >= 1; s >>= 1)
            acc += __shfl_xor(acc, s, 64);

        if (lane == 0)
            out[(long long)(b0 + 8 * k) * N_DIM + n] = acc + bv;

        xr += xstride;
    }
}

extern "C" void kernel_launch(void* const* d_in, const int* in_sizes, int n_in,
                              void* d_out, int out_size, void* d_ws, size_t ws_size,
                              hipStream_t stream) {
    const float* x    = (const float*)d_in[0];   // [B, N, S]
    const float* W    = (const float*)d_in[1];   // [N, S]
    const float* bias = (const float*)d_in[2];   // [N]
    float* out        = (float*)d_out;           // [B, N]

    const int blocks = (B_DIM * N_DIM) / (4 * OUTS_PER_WAVE);  // 2048
    neuron_dot_kernel<<<blocks, 256, 0, stream>>>(x, W, bias, out);
}